// Round 1
// 331.433 us; speedup vs baseline: 1.0010x; 1.0010x over previous
//
#include <hip/hip_runtime.h>
#include <math.h>

#define DIM 8388608
#define NBLK_RED 1024
#define EPS_F 1e-10f

typedef _Float16 h2 __attribute__((ext_vector_type(2)));

// Force v_pk_fma_f16: the naive `a*b + c` on h2 was NOT contracted by hipcc
// (measured ~2x VALU inst count vs the packed-fma floor in rocprof).
static __device__ __forceinline__ h2 h2fma(h2 a, h2 b, h2 c) {
    return __builtin_elementwise_fma(a, b, c);
}

// ws layout (floats):
// [0 .. 4096)    per-block reduction partials: float4 per block {sum g^2, sum d^2, sum g*d, max|g|}
// [4096..4101)   s0, s1, s2, s3 (coeff_k * inv_norm), isq = 1/sqrt(1+it)
// [4104..5065)   h2 (w,w) conv weights/biases:
//                W0[80] B0[20] W1[400] B1[20] W2[400] B2[20] W3[20] B3[1]
#define WS_SCAL 4096
#define WS_WH   4104

__global__ __launch_bounds__(256) void reduce_k(const float4* __restrict__ g4,
                                                const float4* __restrict__ a4,
                                                const float4* __restrict__ b4,
                                                float4* __restrict__ part4) {
    const int N4 = DIM / 4;
    int tid = blockIdx.x * blockDim.x + threadIdx.x;
    int stride = gridDim.x * blockDim.x;
    float ssg = 0.f, ssd = 0.f, sgd = 0.f, mx = 0.f;
    for (int i = tid; i < N4; i += stride) {
        float4 gv = g4[i], av = a4[i], bv = b4[i];
        float d0 = bv.x - av.x, d1 = bv.y - av.y, d2 = bv.z - av.z, d3 = bv.w - av.w;
        ssg = fmaf(gv.x, gv.x, ssg); ssg = fmaf(gv.y, gv.y, ssg);
        ssg = fmaf(gv.z, gv.z, ssg); ssg = fmaf(gv.w, gv.w, ssg);
        ssd = fmaf(d0, d0, ssd); ssd = fmaf(d1, d1, ssd);
        ssd = fmaf(d2, d2, ssd); ssd = fmaf(d3, d3, ssd);
        sgd = fmaf(gv.x, d0, sgd); sgd = fmaf(gv.y, d1, sgd);
        sgd = fmaf(gv.z, d2, sgd); sgd = fmaf(gv.w, d3, sgd);
        mx = fmaxf(mx, fabsf(gv.x)); mx = fmaxf(mx, fabsf(gv.y));
        mx = fmaxf(mx, fabsf(gv.z)); mx = fmaxf(mx, fabsf(gv.w));
    }
    #pragma unroll
    for (int off = 32; off > 0; off >>= 1) {
        ssg += __shfl_down(ssg, off);
        ssd += __shfl_down(ssd, off);
        sgd += __shfl_down(sgd, off);
        mx = fmaxf(mx, __shfl_down(mx, off));
    }
    __shared__ float sm[4][4];
    int lane = threadIdx.x & 63, wid = threadIdx.x >> 6;
    if (lane == 0) { sm[wid][0] = ssg; sm[wid][1] = ssd; sm[wid][2] = sgd; sm[wid][3] = mx; }
    __syncthreads();
    if (threadIdx.x == 0) {
        float t0 = 0.f, t1 = 0.f, t2 = 0.f, t3 = 0.f;
        #pragma unroll
        for (int w = 0; w < 4; ++w) {
            t0 += sm[w][0]; t1 += sm[w][1]; t2 += sm[w][2]; t3 = fmaxf(t3, sm[w][3]);
        }
        part4[blockIdx.x] = make_float4(t0, t1, t2, t3);
    }
}

__global__ __launch_bounds__(64) void mlp_k(float* __restrict__ wsf,
                                            const float* __restrict__ loss_cur,
                                            const float* __restrict__ loss_old,
                                            const int* __restrict__ iter,
                                            const float* __restrict__ lw0, const float* __restrict__ lb0,
                                            const float* __restrict__ lw1, const float* __restrict__ lb1,
                                            const float* __restrict__ lw2, const float* __restrict__ lb2,
                                            const float* __restrict__ lw3, const float* __restrict__ lb3,
                                            const float* __restrict__ cw0, const float* __restrict__ cb0,
                                            const float* __restrict__ cw1, const float* __restrict__ cb1,
                                            const float* __restrict__ cw2, const float* __restrict__ cb2,
                                            const float* __restrict__ cw3, const float* __restrict__ cb3) {
    int t = threadIdx.x;

    // --- convert conv weights to (w,w) packed-half pairs in ws ---
    h2* wh = (h2*)(wsf + WS_WH);
    for (int i = t; i < 80;  i += 64) { _Float16 w = (_Float16)cw0[i]; wh[i]       = (h2){w, w}; }
    for (int i = t; i < 20;  i += 64) { _Float16 w = (_Float16)cb0[i]; wh[80 + i]  = (h2){w, w}; }
    for (int i = t; i < 400; i += 64) { _Float16 w = (_Float16)cw1[i]; wh[100 + i] = (h2){w, w}; }
    for (int i = t; i < 20;  i += 64) { _Float16 w = (_Float16)cb1[i]; wh[500 + i] = (h2){w, w}; }
    for (int i = t; i < 400; i += 64) { _Float16 w = (_Float16)cw2[i]; wh[520 + i] = (h2){w, w}; }
    for (int i = t; i < 20;  i += 64) { _Float16 w = (_Float16)cb2[i]; wh[920 + i] = (h2){w, w}; }
    for (int i = t; i < 20;  i += 64) { _Float16 w = (_Float16)cw3[i]; wh[940 + i] = (h2){w, w}; }
    if (t == 0) { _Float16 w = (_Float16)cb3[0]; wh[960] = (h2){w, w}; }

    // --- final reduction over per-block partials ---
    const float4* part4 = (const float4*)wsf;
    float ssg = 0.f, ssd = 0.f, sgd = 0.f, mx = 0.f;
    for (int b = t; b < NBLK_RED; b += 64) {
        float4 p = part4[b];
        ssg += p.x; ssd += p.y; sgd += p.z; mx = fmaxf(mx, p.w);
    }
    #pragma unroll
    for (int off = 32; off > 0; off >>= 1) {
        ssg += __shfl_down(ssg, off);
        ssd += __shfl_down(ssd, off);
        sgd += __shfl_down(sgd, off);
        mx = fmaxf(mx, __shfl_down(mx, off));
    }
    __shared__ float red[4];
    if (t == 0) { red[0] = ssg; red[1] = ssd; red[2] = sgd; red[3] = mx; }
    __syncthreads();

    __shared__ float buf[32];
    __shared__ float nxt[32];
    float gn = sqrtf(red[0]);
    float dn = sqrtf(red[1]);
    float inv_gn = (gn > EPS_F) ? 1.f / gn : 1.f;
    float inv_dn = (dn > EPS_F) ? 1.f / dn : 1.f;
    float it = (float)iter[0];
    if (t < 6) {
        float f = 0.f;
        if (t == 0) f = log1pf(gn);
        else if (t == 1) f = log1pf(dn);
        else if (t == 2) f = red[2] * inv_gn * inv_dn;
        else if (t == 3) f = red[3] * inv_gn;
        else if (t == 4) f = it;
        else f = logf(loss_cur[0]) - logf(loss_old[0]);
        buf[t] = f;
    }
    __syncthreads();
    float acc;
    if (t < 30) {
        acc = lb0[t];
        #pragma unroll
        for (int c = 0; c < 6; ++c) acc = fmaf(lw0[t * 6 + c], buf[c], acc);
        nxt[t] = fmaxf(acc, 0.f);
    }
    __syncthreads();
    if (t < 20) {
        acc = lb1[t];
        #pragma unroll
        for (int c = 0; c < 30; ++c) acc = fmaf(lw1[t * 30 + c], nxt[c], acc);
        buf[t] = fmaxf(acc, 0.f);
    }
    __syncthreads();
    if (t < 10) {
        acc = lb2[t];
        #pragma unroll
        for (int c = 0; c < 20; ++c) acc = fmaf(lw2[t * 20 + c], buf[c], acc);
        nxt[t] = fmaxf(acc, 0.f);
    }
    __syncthreads();
    if (t < 4) {
        acc = lb3[t];
        #pragma unroll
        for (int c = 0; c < 10; ++c) acc = fmaf(lw3[t * 10 + c], nxt[c], acc);
        float s = ((t & 1) == 0) ? acc * inv_gn : acc * inv_dn;  // t=0,2 g-path; t=1,3 d-path
        wsf[WS_SCAL + t] = s;
    }
    if (t == 0) wsf[WS_SCAL + 4] = rsqrtf(1.f + it);
}

__global__ __launch_bounds__(256) void apply_k(const float4* __restrict__ g4,
                                               const float4* __restrict__ a4,
                                               const float4* __restrict__ b4,
                                               const float4* __restrict__ gp4,
                                               const float4* __restrict__ ex4,
                                               const float* __restrict__ wsf,
                                               float4* __restrict__ out4) {
    // uniform scalars (scalar loads)
    float s0 = wsf[WS_SCAL + 0], s1 = wsf[WS_SCAL + 1];
    float s2 = wsf[WS_SCAL + 2], s3 = wsf[WS_SCAL + 3];
    float isq = wsf[WS_SCAL + 4];
    const h2* __restrict__ wh = (const h2*)(wsf + WS_WH);
    const h2* W0 = wh;        const h2* B0 = wh + 80;
    const h2* W1 = wh + 100;  const h2* B1 = wh + 500;
    const h2* W2 = wh + 520;  const h2* B2 = wh + 920;
    const h2* W3 = wh + 940;  const h2  B3v = wh[960];

    int i = blockIdx.x * blockDim.x + threadIdx.x;   // exactly DIM/4 threads
    float4 gv = g4[i], av = a4[i], bv = b4[i], pv = gp4[i], ev = ex4[i];
    float st[4] = {bv.x, bv.y, bv.z, bv.w};
    float de[4] = {bv.x - av.x, bv.y - av.y, bv.z - av.z, bv.w - av.w};
    float gg[4] = {gv.x, gv.y, gv.z, gv.w};
    float pp[4] = {pv.x, pv.y, pv.z, pv.w};
    float ee[4] = {ev.x, ev.y, ev.z, ev.w};

    // x channels as packed pairs: pair p covers elements {2p, 2p+1}
    h2 xh[2][4];
    #pragma unroll
    for (int p = 0; p < 2; ++p) {
        int e0 = 2 * p, e1 = 2 * p + 1;
        xh[p][0] = (h2){(_Float16)(s0 * pp[e0] * gg[e0]), (_Float16)(s0 * pp[e1] * gg[e1])};
        xh[p][1] = (h2){(_Float16)(s1 * ee[e0] * de[e0]), (_Float16)(s1 * ee[e1] * de[e1])};
        xh[p][2] = (h2){(_Float16)(s2 * gg[e0]), (_Float16)(s2 * gg[e1])};
        xh[p][3] = (h2){(_Float16)(s3 * de[e0]), (_Float16)(s3 * de[e1])};
    }

    const h2 zero = (h2){(_Float16)0.f, (_Float16)0.f};
    h2 h[2][20], hb[2][20];
    // layer0: 4 -> 20, relu
    #pragma unroll
    for (int o = 0; o < 20; ++o) {
        h2 b = B0[o];
        h2 c0 = b, c1 = b;
        #pragma unroll
        for (int c = 0; c < 4; ++c) {
            h2 wv = W0[o * 4 + c];
            c0 = h2fma(wv, xh[0][c], c0);
            c1 = h2fma(wv, xh[1][c], c1);
        }
        h[0][o] = __builtin_elementwise_max(c0, zero);
        h[1][o] = __builtin_elementwise_max(c1, zero);
    }
    // layer1: 20 -> 20, relu
    #pragma unroll
    for (int o = 0; o < 20; ++o) {
        h2 b = B1[o];
        h2 c0 = b, c1 = b;
        #pragma unroll
        for (int c = 0; c < 20; ++c) {
            h2 wv = W1[o * 20 + c];
            c0 = h2fma(wv, h[0][c], c0);
            c1 = h2fma(wv, h[1][c], c1);
        }
        hb[0][o] = __builtin_elementwise_max(c0, zero);
        hb[1][o] = __builtin_elementwise_max(c1, zero);
    }
    // layer2: 20 -> 20, relu
    #pragma unroll
    for (int o = 0; o < 20; ++o) {
        h2 b = B2[o];
        h2 c0 = b, c1 = b;
        #pragma unroll
        for (int c = 0; c < 20; ++c) {
            h2 wv = W2[o * 20 + c];
            c0 = h2fma(wv, hb[0][c], c0);
            c1 = h2fma(wv, hb[1][c], c1);
        }
        h[0][o] = __builtin_elementwise_max(c0, zero);
        h[1][o] = __builtin_elementwise_max(c1, zero);
    }
    // layer3: 20 -> 1 (no relu)
    h2 d0 = B3v, d1 = B3v;
    #pragma unroll
    for (int c = 0; c < 20; ++c) {
        h2 wv = W3[c];
        d0 = h2fma(wv, h[0][c], d0);
        d1 = h2fma(wv, h[1][c], d1);
    }
    float4 outv;
    outv.x = fmaf((float)d0[0], isq, st[0]);
    outv.y = fmaf((float)d0[1], isq, st[1]);
    outv.z = fmaf((float)d1[0], isq, st[2]);
    outv.w = fmaf((float)d1[1], isq, st[3]);
    out4[i] = outv;
}

extern "C" void kernel_launch(void* const* d_in, const int* in_sizes, int n_in,
                              void* d_out, int out_size, void* d_ws, size_t ws_size,
                              hipStream_t stream) {
    const float* grad    = (const float*)d_in[0];
    const float* state0  = (const float*)d_in[1];
    const float* state1  = (const float*)d_in[2];
    const float* losscur = (const float*)d_in[3];
    const float* lossold = (const float*)d_in[4];
    const int*   iter    = (const int*)d_in[5];
    const float* gparam  = (const float*)d_in[6];
    const float* extrap  = (const float*)d_in[7];
    const float* cw0 = (const float*)d_in[8];  const float* cb0 = (const float*)d_in[9];
    const float* cw1 = (const float*)d_in[10]; const float* cb1 = (const float*)d_in[11];
    const float* cw2 = (const float*)d_in[12]; const float* cb2 = (const float*)d_in[13];
    const float* cw3 = (const float*)d_in[14]; const float* cb3 = (const float*)d_in[15];
    const float* lw0 = (const float*)d_in[16]; const float* lb0 = (const float*)d_in[17];
    const float* lw1 = (const float*)d_in[18]; const float* lb1 = (const float*)d_in[19];
    const float* lw2 = (const float*)d_in[20]; const float* lb2 = (const float*)d_in[21];
    const float* lw3 = (const float*)d_in[22]; const float* lb3 = (const float*)d_in[23];

    float* wsf = (float*)d_ws;
    float* out = (float*)d_out;

    reduce_k<<<NBLK_RED, 256, 0, stream>>>((const float4*)grad, (const float4*)state0,
                                           (const float4*)state1, (float4*)wsf);

    mlp_k<<<1, 64, 0, stream>>>(wsf, losscur, lossold, iter,
                                lw0, lb0, lw1, lb1, lw2, lb2, lw3, lb3,
                                cw0, cb0, cw1, cb1, cw2, cb2, cw3, cb3);

    apply_k<<<DIM / 4 / 256, 256, 0, stream>>>((const float4*)grad, (const float4*)state0,
                                               (const float4*)state1, (const float4*)gparam,
                                               (const float4*)extrap,
                                               wsf, (float4*)out);
}

// Round 3
// 266.535 us; speedup vs baseline: 1.2447x; 1.2435x over previous
//
#include <hip/hip_runtime.h>
#include <math.h>

#define DIM 8388608
#define NBLK_RED 1024
#define EPS_F 1e-10f

typedef _Float16 h2 __attribute__((ext_vector_type(2)));
typedef _Float16 h4 __attribute__((ext_vector_type(4)));
typedef __fp16 g2 __attribute__((ext_vector_type(2)));   // __builtin_amdgcn_cvt_pkrtz return type
typedef float f32x16 __attribute__((ext_vector_type(16)));

// ws layout (floats):
// [0 .. 4096)    per-block reduction partials: float4 per block {sum g^2, sum d^2, sum g*d, max|g|}
// [4096..4101)   s0, s1, s2, s3 (coeff_k * inv_norm), isq = 1/sqrt(1+it)
// [4104..5384)   MFMA A-fragment weight table: uint2[10 frags][64 lanes]
//                frag f, lane l: 4 f16 = W_aug[row = l&31][k = k0(f) + (l>>5)*4 + j]
//                W_aug = [W | bias | 0-pad] (bias as constant-1.0 input channel)
//                f0: L0 (20x4,k0=0); f1-3: L1 (20x20,k0=0/8/16); f4-6: L2; f7-9: L3 (1x20)
#define WS_SCAL 4096
#define WS_FRG  4104

static __device__ __forceinline__ unsigned h2_bits(h2 v) {
    union { h2 h; unsigned u; } c; c.h = v; return c.u;
}
static __device__ __forceinline__ h4 h4_from(unsigned lo, unsigned hi) {
    union { unsigned u[2]; h4 h; } c; c.u[0] = lo; c.u[1] = hi; return c.h;
}
// v_cvt_pkrtz_f16_f32 with a bit-cast to our _Float16 vector type
// (the builtin returns __fp16x2; clang refuses implicit conversion).
static __device__ __forceinline__ h2 pkrtz(float a, float b) {
    union { g2 g; h2 h; } c; c.g = __builtin_amdgcn_cvt_pkrtz(a, b); return c.h;
}
static __device__ __forceinline__ h2 relu_pk(h2 v) {
    const h2 z = {(_Float16)0.f, (_Float16)0.f};
    return __builtin_elementwise_max(v, z);
}
// B-frag from accumulator regs [RB..RB+3]: relu + cvt to f16.
// D row layout (r&3)+8*(r>>2)+4*(lane>>5) == B k layout 4*(lane>>5)+j per 8-k
// block, so accumulator regs ARE the next layer's B fragment (no permute).
template<int RB>
static __device__ __forceinline__ h4 bfrag(f32x16 a) {
    h2 lo = relu_pk(pkrtz(a[RB],     a[RB + 1]));
    h2 hi = relu_pk(pkrtz(a[RB + 2], a[RB + 3]));
    return h4_from(h2_bits(lo), h2_bits(hi));
}
// Same, but upper half-wave carries the constant-1.0 bias channel at its j=0
// slot (k=20) instead of data (its rows 20-23 are zero-padding anyway).
template<int RB>
static __device__ __forceinline__ h4 bfrag_bias(f32x16 a, bool up) {
    h2 lo = relu_pk(pkrtz(a[RB],     a[RB + 1]));
    h2 hi = relu_pk(pkrtz(a[RB + 2], a[RB + 3]));
    unsigned u0 = up ? 0x00003C00u : h2_bits(lo);   // fp16 1.0 in low half
    unsigned u1 = up ? 0u          : h2_bits(hi);
    return h4_from(u0, u1);
}
#define MFMA8(a, b, c) __builtin_amdgcn_mfma_f32_32x32x8f16((a), (b), (c), 0, 0, 0)

__global__ __launch_bounds__(256) void reduce_k(const float4* __restrict__ g4,
                                                const float4* __restrict__ a4,
                                                const float4* __restrict__ b4,
                                                float4* __restrict__ part4) {
    const int N4 = DIM / 4;
    int tid = blockIdx.x * blockDim.x + threadIdx.x;
    int stride = gridDim.x * blockDim.x;
    float ssg = 0.f, ssd = 0.f, sgd = 0.f, mx = 0.f;
    for (int i = tid; i < N4; i += stride) {
        float4 gv = g4[i], av = a4[i], bv = b4[i];
        float d0 = bv.x - av.x, d1 = bv.y - av.y, d2 = bv.z - av.z, d3 = bv.w - av.w;
        ssg = fmaf(gv.x, gv.x, ssg); ssg = fmaf(gv.y, gv.y, ssg);
        ssg = fmaf(gv.z, gv.z, ssg); ssg = fmaf(gv.w, gv.w, ssg);
        ssd = fmaf(d0, d0, ssd); ssd = fmaf(d1, d1, ssd);
        ssd = fmaf(d2, d2, ssd); ssd = fmaf(d3, d3, ssd);
        sgd = fmaf(gv.x, d0, sgd); sgd = fmaf(gv.y, d1, sgd);
        sgd = fmaf(gv.z, d2, sgd); sgd = fmaf(gv.w, d3, sgd);
        mx = fmaxf(mx, fabsf(gv.x)); mx = fmaxf(mx, fabsf(gv.y));
        mx = fmaxf(mx, fabsf(gv.z)); mx = fmaxf(mx, fabsf(gv.w));
    }
    #pragma unroll
    for (int off = 32; off > 0; off >>= 1) {
        ssg += __shfl_down(ssg, off);
        ssd += __shfl_down(ssd, off);
        sgd += __shfl_down(sgd, off);
        mx = fmaxf(mx, __shfl_down(mx, off));
    }
    __shared__ float sm[4][4];
    int lane = threadIdx.x & 63, wid = threadIdx.x >> 6;
    if (lane == 0) { sm[wid][0] = ssg; sm[wid][1] = ssd; sm[wid][2] = sgd; sm[wid][3] = mx; }
    __syncthreads();
    if (threadIdx.x == 0) {
        float t0 = 0.f, t1 = 0.f, t2 = 0.f, t3 = 0.f;
        #pragma unroll
        for (int w = 0; w < 4; ++w) {
            t0 += sm[w][0]; t1 += sm[w][1]; t2 += sm[w][2]; t3 = fmaxf(t3, sm[w][3]);
        }
        part4[blockIdx.x] = make_float4(t0, t1, t2, t3);
    }
}

// Augmented weight fetch: [W | bias-at-k==cols | zeros]
static __device__ __forceinline__ float waug(const float* __restrict__ W,
                                             const float* __restrict__ B,
                                             int rows, int cols, int i, int k) {
    if (i >= rows) return 0.f;
    if (k < cols)  return W[i * cols + k];
    if (k == cols) return B[i];
    return 0.f;
}
static __device__ __forceinline__ uint2 mkfrag(const float* __restrict__ W,
                                               const float* __restrict__ B,
                                               int rows, int cols, int i, int k0) {
    h2 lo = {(_Float16)waug(W, B, rows, cols, i, k0),
             (_Float16)waug(W, B, rows, cols, i, k0 + 1)};
    h2 hi = {(_Float16)waug(W, B, rows, cols, i, k0 + 2),
             (_Float16)waug(W, B, rows, cols, i, k0 + 3)};
    return make_uint2(h2_bits(lo), h2_bits(hi));
}

__global__ __launch_bounds__(64) void mlp_k(float* __restrict__ wsf,
                                            const float* __restrict__ loss_cur,
                                            const float* __restrict__ loss_old,
                                            const int* __restrict__ iter,
                                            const float* __restrict__ lw0, const float* __restrict__ lb0,
                                            const float* __restrict__ lw1, const float* __restrict__ lb1,
                                            const float* __restrict__ lw2, const float* __restrict__ lb2,
                                            const float* __restrict__ lw3, const float* __restrict__ lb3,
                                            const float* __restrict__ cw0, const float* __restrict__ cb0,
                                            const float* __restrict__ cw1, const float* __restrict__ cb1,
                                            const float* __restrict__ cw2, const float* __restrict__ cb2,
                                            const float* __restrict__ cw3, const float* __restrict__ cb3) {
    int t = threadIdx.x;

    // --- pack conv weights into per-lane MFMA A-fragments ---
    uint2* frg = (uint2*)(wsf + WS_FRG);
    int i = t & 31, kb = (t >> 5) * 4;
    frg[0 * 64 + t] = mkfrag(cw0, cb0, 20, 4,  i, kb);
    frg[1 * 64 + t] = mkfrag(cw1, cb1, 20, 20, i, kb);
    frg[2 * 64 + t] = mkfrag(cw1, cb1, 20, 20, i, 8 + kb);
    frg[3 * 64 + t] = mkfrag(cw1, cb1, 20, 20, i, 16 + kb);
    frg[4 * 64 + t] = mkfrag(cw2, cb2, 20, 20, i, kb);
    frg[5 * 64 + t] = mkfrag(cw2, cb2, 20, 20, i, 8 + kb);
    frg[6 * 64 + t] = mkfrag(cw2, cb2, 20, 20, i, 16 + kb);
    frg[7 * 64 + t] = mkfrag(cw3, cb3, 1,  20, i, kb);
    frg[8 * 64 + t] = mkfrag(cw3, cb3, 1,  20, i, 8 + kb);
    frg[9 * 64 + t] = mkfrag(cw3, cb3, 1,  20, i, 16 + kb);

    // --- final reduction over per-block partials ---
    const float4* part4 = (const float4*)wsf;
    float ssg = 0.f, ssd = 0.f, sgd = 0.f, mx = 0.f;
    for (int b = t; b < NBLK_RED; b += 64) {
        float4 p = part4[b];
        ssg += p.x; ssd += p.y; sgd += p.z; mx = fmaxf(mx, p.w);
    }
    #pragma unroll
    for (int off = 32; off > 0; off >>= 1) {
        ssg += __shfl_down(ssg, off);
        ssd += __shfl_down(ssd, off);
        sgd += __shfl_down(sgd, off);
        mx = fmaxf(mx, __shfl_down(mx, off));
    }
    __shared__ float red[4];
    if (t == 0) { red[0] = ssg; red[1] = ssd; red[2] = sgd; red[3] = mx; }
    __syncthreads();

    __shared__ float buf[32];
    __shared__ float nxt[32];
    float gn = sqrtf(red[0]);
    float dn = sqrtf(red[1]);
    float inv_gn = (gn > EPS_F) ? 1.f / gn : 1.f;
    float inv_dn = (dn > EPS_F) ? 1.f / dn : 1.f;
    float it = (float)iter[0];
    if (t < 6) {
        float f = 0.f;
        if (t == 0) f = log1pf(gn);
        else if (t == 1) f = log1pf(dn);
        else if (t == 2) f = red[2] * inv_gn * inv_dn;
        else if (t == 3) f = red[3] * inv_gn;
        else if (t == 4) f = it;
        else f = logf(loss_cur[0]) - logf(loss_old[0]);
        buf[t] = f;
    }
    __syncthreads();
    float acc;
    if (t < 30) {
        acc = lb0[t];
        #pragma unroll
        for (int c = 0; c < 6; ++c) acc = fmaf(lw0[t * 6 + c], buf[c], acc);
        nxt[t] = fmaxf(acc, 0.f);
    }
    __syncthreads();
    if (t < 20) {
        acc = lb1[t];
        #pragma unroll
        for (int c = 0; c < 30; ++c) acc = fmaf(lw1[t * 30 + c], nxt[c], acc);
        buf[t] = fmaxf(acc, 0.f);
    }
    __syncthreads();
    if (t < 10) {
        acc = lb2[t];
        #pragma unroll
        for (int c = 0; c < 20; ++c) acc = fmaf(lw2[t * 20 + c], buf[c], acc);
        nxt[t] = fmaxf(acc, 0.f);
    }
    __syncthreads();
    if (t < 4) {
        acc = lb3[t];
        #pragma unroll
        for (int c = 0; c < 10; ++c) acc = fmaf(lw3[t * 10 + c], nxt[c], acc);
        float s = ((t & 1) == 0) ? acc * inv_gn : acc * inv_dn;  // t=0,2 g-path; t=1,3 d-path
        wsf[WS_SCAL + t] = s;
    }
    if (t == 0) wsf[WS_SCAL + 4] = rsqrtf(1.f + it);
}

// MFMA conv stack: each wave handles 256 elements (8 tiles of 32 columns).
// Layer chain is permute-free: acc regs {0-3,4-7,8-11} of layer N are directly
// the three K=8 B-fragments of layer N+1 (row/k index structures coincide).
__global__ __launch_bounds__(256) void apply_k(const float4* __restrict__ g4,
                                               const float4* __restrict__ a4,
                                               const float4* __restrict__ b4,
                                               const float4* __restrict__ gp4,
                                               const float4* __restrict__ ex4,
                                               const float* __restrict__ wsf,
                                               float4* __restrict__ out4) {
    __shared__ uint2 xs[4][256];                    // per-elem packed x channels (4 f16)
    __shared__ __align__(16) float os[4][256];      // per-elem conv output (f32)

    const int lane = threadIdx.x & 63;
    const int wv   = threadIdx.x >> 6;
    const bool up  = lane >= 32;

    const float s0 = wsf[WS_SCAL + 0], s1 = wsf[WS_SCAL + 1];
    const float s2 = wsf[WS_SCAL + 2], s3 = wsf[WS_SCAL + 3];
    const float isq = wsf[WS_SCAL + 4];

    // weight A-fragments (pre-packed by mlp_k), 8B/lane coalesced
    const uint2* __restrict__ frg = (const uint2*)(wsf + WS_FRG);
    h4 wf[10];
    #pragma unroll
    for (int f = 0; f < 10; ++f) {
        uint2 u = frg[f * 64 + lane];
        wf[f] = h4_from(u.x, u.y);
    }

    const int i4 = blockIdx.x * 256 + threadIdx.x;  // this thread's float4 slot
    float4 gv = g4[i4], av = a4[i4], bv = b4[i4], pv = gp4[i4], ev = ex4[i4];
    float GG[4] = {gv.x, gv.y, gv.z, gv.w};
    float PP[4] = {pv.x, pv.y, pv.z, pv.w};
    float EE[4] = {ev.x, ev.y, ev.z, ev.w};
    float DE[4] = {bv.x - av.x, bv.y - av.y, bv.z - av.z, bv.w - av.w};

    // stage x channels to LDS: 4 f16 per element {x0,x1,x2,x3} = B k=0..3
    #pragma unroll
    for (int e = 0; e < 4; ++e) {
        float x0 = s0 * PP[e] * GG[e];
        float x1 = s1 * EE[e] * DE[e];
        float x2 = s2 * GG[e];
        float x3 = s3 * DE[e];
        h2 lo = pkrtz(x0, x1);
        h2 hi = pkrtz(x2, x3);
        xs[wv][(lane << 2) + e] = make_uint2(h2_bits(lo), h2_bits(hi));
    }
    __syncthreads();

    f32x16 Z;
    #pragma unroll
    for (int k = 0; k < 16; ++k) Z[k] = 0.f;

    #pragma unroll
    for (int tl = 0; tl < 8; ++tl) {
        uint2 xv = xs[wv][(tl << 5) + (lane & 31)];
        // L0 B: lower half-wave k=0..3 (data), upper k=4 is the 1.0 bias channel
        h4 b0 = h4_from(up ? 0x00003C00u : xv.x, up ? 0u : xv.y);
        f32x16 a0 = MFMA8(wf[0], b0, Z);

        h4 p0 = bfrag<0>(a0), p1 = bfrag<4>(a0), p2 = bfrag_bias<8>(a0, up);
        f32x16 a1 = MFMA8(wf[1], p0, Z);
        a1 = MFMA8(wf[2], p1, a1);
        a1 = MFMA8(wf[3], p2, a1);

        h4 q0 = bfrag<0>(a1), q1 = bfrag<4>(a1), q2 = bfrag_bias<8>(a1, up);
        f32x16 a2 = MFMA8(wf[4], q0, Z);
        a2 = MFMA8(wf[5], q1, a2);
        a2 = MFMA8(wf[6], q2, a2);

        h4 r0 = bfrag<0>(a2), r1 = bfrag<4>(a2), r2 = bfrag_bias<8>(a2, up);
        f32x16 a3 = MFMA8(wf[7], r0, Z);
        a3 = MFMA8(wf[8], r1, a3);
        a3 = MFMA8(wf[9], r2, a3);

        // direction for this tile's 32 columns lives in reg0 of lanes 0-31
        if (lane < 32) os[wv][(tl << 5) + lane] = a3[0];
    }
    __syncthreads();

    const float4 ov = *reinterpret_cast<const float4*>(&os[wv][lane << 2]);
    float4 outv;
    outv.x = fmaf(ov.x, isq, bv.x);
    outv.y = fmaf(ov.y, isq, bv.y);
    outv.z = fmaf(ov.z, isq, bv.z);
    outv.w = fmaf(ov.w, isq, bv.w);
    out4[i4] = outv;
}

extern "C" void kernel_launch(void* const* d_in, const int* in_sizes, int n_in,
                              void* d_out, int out_size, void* d_ws, size_t ws_size,
                              hipStream_t stream) {
    const float* grad    = (const float*)d_in[0];
    const float* state0  = (const float*)d_in[1];
    const float* state1  = (const float*)d_in[2];
    const float* losscur = (const float*)d_in[3];
    const float* lossold = (const float*)d_in[4];
    const int*   iter    = (const int*)d_in[5];
    const float* gparam  = (const float*)d_in[6];
    const float* extrap  = (const float*)d_in[7];
    const float* cw0 = (const float*)d_in[8];  const float* cb0 = (const float*)d_in[9];
    const float* cw1 = (const float*)d_in[10]; const float* cb1 = (const float*)d_in[11];
    const float* cw2 = (const float*)d_in[12]; const float* cb2 = (const float*)d_in[13];
    const float* cw3 = (const float*)d_in[14]; const float* cb3 = (const float*)d_in[15];
    const float* lw0 = (const float*)d_in[16]; const float* lb0 = (const float*)d_in[17];
    const float* lw1 = (const float*)d_in[18]; const float* lb1 = (const float*)d_in[19];
    const float* lw2 = (const float*)d_in[20]; const float* lb2 = (const float*)d_in[21];
    const float* lw3 = (const float*)d_in[22]; const float* lb3 = (const float*)d_in[23];

    float* wsf = (float*)d_ws;
    float* out = (float*)d_out;

    reduce_k<<<NBLK_RED, 256, 0, stream>>>((const float4*)grad, (const float4*)state0,
                                           (const float4*)state1, (float4*)wsf);

    mlp_k<<<1, 64, 0, stream>>>(wsf, losscur, lossold, iter,
                                lw0, lb0, lw1, lb1, lw2, lb2, lw3, lb3,
                                cw0, cb0, cw1, cb1, cw2, cb2, cw3, cb3);

    apply_k<<<DIM / 1024, 256, 0, stream>>>((const float4*)grad, (const float4*)state0,
                                            (const float4*)state1, (const float4*)gparam,
                                            (const float4*)extrap,
                                            wsf, (float4*)out);
}